// Round 14
// baseline (484.668 us; speedup 1.0000x reference)
//
#include <hip/hip_runtime.h>

typedef unsigned short u16;
typedef unsigned int   u32;

typedef __attribute__((ext_vector_type(8))) short short8v;
typedef __attribute__((ext_vector_type(4))) float f32x4;

// ---------------- problem constants ----------------
#define BQ   8192
#define DIN  1024
#define DHID 2048
#define DOUT 1024
#define NE   16
#define NSLOT (BQ*2)
#define MAXT 144         // sum ceil(cnt_e/128) <= 128 + 16

// ---------------- ws layout (bytes) ----------------
#define OFF_CNT    ((size_t)0)
#define OFF_CURSOR ((size_t)64)
#define OFF_PREFIX ((size_t)128)
#define OFF_TTAB   ((size_t)512)
#define OFF_NTT    ((size_t)2048)
#define OFF_TOPIDX ((size_t)4096)
#define OFF_TOPW   (OFF_TOPIDX + (size_t)65536)
#define OFF_SLOTS  (OFF_TOPW   + (size_t)65536)
#define MB (size_t)(1u<<20)
#define OFF_XB     (1*MB)
#define OFF_W1T    (OFF_XB  + 16*MB)
#define OFF_W2T    (OFF_W1T + 64*MB)
#define OFF_H      (OFF_W2T + 64*MB)

__device__ __forceinline__ u16 f2b(float f) {        // f32 -> bf16 RNE
  u32 u = __float_as_uint(f);
  u += 0x7fffu + ((u >> 16) & 1u);
  return (u16)(u >> 16);
}

__device__ __forceinline__ void gl16(const void* g, void* l) {
  __builtin_amdgcn_global_load_lds(
      (const __attribute__((address_space(1))) u32*)g,
      (__attribute__((address_space(3))) u32*)l, 16, 0, 0);
}

__device__ __forceinline__ int imin(int a, int b) { return a < b ? a : b; }

// bijective XCD-chunked block swizzle (m204)
__device__ __forceinline__ int xcd_swz(int L, int total) {
  int q = total >> 3, r = total & 7;
  int c = L & 7, p = L >> 3;
  return (c < r ? c * (q + 1) : r * (q + 1) + (c - r) * q) + p;
}

#define FENCE asm volatile("" ::: "memory")
#define BAR   do { FENCE; __builtin_amdgcn_s_barrier(); FENCE; } while (0)
#define MFMA  __builtin_amdgcn_mfma_f32_16x16x32_bf16

// ------- prepass: per-expert transpose+convert: in[R][C] f32 -> out[C][R] bf16 -------
__global__ void transpose_conv_k(const float* __restrict__ in, u16* __restrict__ out,
                                 int R, int C) {
  __shared__ __align__(16) u16 tile[64][68];
  const int e = blockIdx.z;
  const float* ip = in + (size_t)e * R * C;
  u16* op = out + (size_t)e * R * C;
  const int r0 = blockIdx.y * 64, c0 = blockIdx.x * 64;
  const int tr = threadIdx.x >> 4, tc = threadIdx.x & 15;
#pragma unroll
  for (int i = 0; i < 4; ++i) {
    int r = tr + i * 16;
    float4 v = *(const float4*)(ip + (size_t)(r0 + r) * C + c0 + tc * 4);
    ushort4 b; b.x=f2b(v.x); b.y=f2b(v.y); b.z=f2b(v.z); b.w=f2b(v.w);
    *(ushort4*)&tile[r][tc * 4] = b;
  }
  __syncthreads();
#pragma unroll
  for (int i = 0; i < 4; ++i) {
    int c = i * 16 + (threadIdx.x >> 4);
    int rq = threadIdx.x & 15;
    ushort4 b;
    b.x = tile[rq*4+0][c]; b.y = tile[rq*4+1][c];
    b.z = tile[rq*4+2][c]; b.w = tile[rq*4+3][c];
    *(ushort4*)(op + (size_t)(c0 + c) * R + r0 + rq * 4) = b;
  }
}

// ---------- gating (+ fused x->bf16 convert): Wg in LDS, 8 thr/token, fp64 ----------
__global__ __launch_bounds__(256) void gating2_k(
    const float* __restrict__ x, const float* __restrict__ Wg,
    int2* __restrict__ topidx, float2* __restrict__ topw, int* __restrict__ cnt,
    u16* __restrict__ xb) {
  __shared__ __align__(16) float wg[1024 * 16];
  __shared__ int hist[16];
  const int tid = threadIdx.x;
  const int t0 = blockIdx.x * 32;
  if (tid < 16) hist[tid] = 0;
  for (int idx = tid; idx < 4096; idx += 256) {
    int k = idx >> 2, c = idx & 3;
    float4 v = ((const float4*)Wg)[idx];
    int pc = c ^ ((k >> 7) & 3);
    *(float4*)&wg[k * 16 + pc * 4] = v;
  }
  __syncthreads();
  const int tt = tid >> 3, q = tid & 7;
  const int f = q & 3;
  double p[16];
#pragma unroll
  for (int e = 0; e < 16; ++e) p[e] = 0.0;
  const float4* xr4 = (const float4*)(x + (size_t)(t0 + tt) * DIN + q * 128);
  for (int jj = 0; jj < 32; ++jj) {
    float4 xv = xr4[jj];
#pragma unroll
    for (int u = 0; u < 4; ++u) {
      int row = q * 128 + jj * 4 + u;
      float xs = (u == 0) ? xv.x : (u == 1) ? xv.y : (u == 2) ? xv.z : xv.w;
      double xd = (double)xs;
#pragma unroll
      for (int c = 0; c < 4; ++c) {
        float4 w = *(const float4*)&wg[row * 16 + (c ^ f) * 4];
        p[c * 4 + 0] += xd * (double)w.x;
        p[c * 4 + 1] += xd * (double)w.y;
        p[c * 4 + 2] += xd * (double)w.z;
        p[c * 4 + 3] += xd * (double)w.w;
      }
    }
  }
#pragma unroll
  for (int e = 0; e < 16; ++e) {
    double v = p[e];
    v += __shfl_xor(v, 1);
    v += __shfl_xor(v, 2);
    v += __shfl_xor(v, 4);
    p[e] = v;
  }
  if (q == 0) {
    double m0 = -1e300, m1 = -1e300; int i0 = 0, i1 = 0;
#pragma unroll
    for (int e = 0; e < 16; ++e) {
      double v = p[e];
      if (v > m0) { m1 = m0; i1 = i0; m0 = v; i0 = e; }
      else if (v > m1) { m1 = v; i1 = e; }
    }
    double r = exp(m1 - m0);
    double w0 = 1.0 / (1.0 + r);
    int t = t0 + tt;
    topidx[t] = make_int2(i0, i1);
    topw[t] = make_float2((float)w0, (float)(r / (1.0 + r)));
    atomicAdd(&hist[i0], 1);
    atomicAdd(&hist[i1], 1);
  }
  // fused convert of this block's 32 token rows (x hot in L1/L2)
  const float4* ip = (const float4*)x;
#pragma unroll
  for (int i = 0; i < 16; ++i) {
    int idx = i * 256 + tid;
    size_t g = (size_t)t0 * 128 + idx;
    float4 a = ip[g * 2], b = ip[g * 2 + 1];
    union { u16 u[8]; uint4 v; } r;
    r.u[0]=f2b(a.x); r.u[1]=f2b(a.y); r.u[2]=f2b(a.z); r.u[3]=f2b(a.w);
    r.u[4]=f2b(b.x); r.u[5]=f2b(b.y); r.u[6]=f2b(b.z); r.u[7]=f2b(b.w);
    ((uint4*)xb)[g] = r.v;
  }
  __syncthreads();
  if (tid < 16 && hist[tid] > 0) atomicAdd(&cnt[tid], hist[tid]);
}

// prefix + compact tile table: entries (e<<16)|mt, mt over ceil(cnt/128)
__global__ void prefix_k(const int* __restrict__ cnt, int* __restrict__ prefix,
                         int* __restrict__ cursor, u32* __restrict__ ttab,
                         int* __restrict__ ntt) {
  if (threadIdx.x == 0) {
    int s = 0, nt = 0;
    for (int e = 0; e < 16; ++e) {
      prefix[e] = s; cursor[e] = s; s += cnt[e];
      int mts = (cnt[e] + 127) >> 7;
      for (int m = 0; m < mts; ++m) ttab[nt++] = ((u32)e << 16) | (u32)m;
    }
    prefix[16] = s;
    *ntt = nt;
  }
}

__global__ void scatter_k(const int2* __restrict__ topidx, int* __restrict__ cursor,
                          int* __restrict__ slots) {
  int t = blockIdx.x * 256 + threadIdx.x;
  int2 e = topidx[t];
  int p0 = atomicAdd(&cursor[e.x], 1); slots[p0] = t * 2 + 0;
  int p1 = atomicAdd(&cursor[e.y], 1); slots[p1] = t * 2 + 1;
}

// =====================================================================
// grouped GEMM: BM=128, BN=256, BK=64, 512 thr (8 waves, 2Mx4N, 64x64/wave).
// 2 phases/K-tile, 16 MFMA/phase. LDS: 2 buf x {A 16KB | Blo 16KB | Bhi 16KB}
// = 96KB. Stage units: ph1 -> Bhi(t+1); ph2 -> A(t+2), Blo(t+2).
// Boundary s_waitcnt vmcnt(4): 4 newest = {A(t+2),Blo(t+2)} => t+1 landed.
// Chunk swizzle: phys 16B chunk = global chunk ^ (row&7), both sides.
// (round-11 structure, verified passing; all addresses consumed by the
// prologue so no global load can sink into the counted-vmcnt loop.)
// =====================================================================

// -------- GEMM 1: H = relu(gather(xb) @ W1 + b1) --------
__global__ __launch_bounds__(512, 1) void mlp1_k(
    const u16* __restrict__ xb, const u16* __restrict__ W1T,
    const float* __restrict__ b1, const int* __restrict__ slots,
    const int* __restrict__ prefix, const int* __restrict__ cnt,
    const u32* __restrict__ ttab, const int* __restrict__ ntt,
    u16* __restrict__ H) {
  const int ntt_ = *ntt;
  const int tot = 8 * ntt_;                    // nbx = DHID/256 = 8
  int L = blockIdx.x;
  if (L >= tot) return;
  int w = xcd_swz(L, tot);
  const int bx = w / ntt_, ti = w - bx * ntt_;
  const u32 ent = ttab[ti];
  const int e = (int)(ent >> 16), mt = (int)(ent & 0xffffu);
  const int cn = cnt[e], base = prefix[e];
  const int n0 = bx * 256;
  __shared__ __align__(16) u16 lds[49152];     // 96KB
  const int tid = threadIdx.x, lane = tid & 63, wid = tid >> 6;
  const int l15 = lane & 15, lq = lane >> 4;
  const int tr = tid >> 3;
  const u32 swzo = (u32)(((tid & 7) ^ (tr & 7)) * 16);
  // staging sources: A rows j*64+tr (128 rows), B rows h*128+j*64+tr (256 rows)
  u32 aofs[2], bofs[2][2];
#pragma unroll
  for (int j = 0; j < 2; ++j) {
    int r = j * 64 + tr;
    int sidx = imin(base + mt * 128 + r, NSLOT - 1);
    int tok = slots[sidx] >> 1;
    aofs[j] = (u32)tok * 2048u + swzo;
#pragma unroll
    for (int h = 0; h < 2; ++h)
      bofs[h][j] = (u32)(e * 2048 + n0 + h * 128 + j * 64 + tr) * 2048u + swzo;
  }
  const char* aptr = (const char*)xb;
  const char* bptr = (const char*)W1T;
  int aoff[4], boff[4];
#pragma unroll
  for (int m = 0; m < 4; ++m) {
    int r = (wid >> 2) * 64 + m * 16 + l15;
    aoff[m] = r * 64 + ((lq ^ (r & 7)) * 8);
  }
#pragma unroll
  for (int n = 0; n < 4; ++n) {
    int r = (wid & 3) * 64 + n * 16 + l15;
    boff[n] = 8192 + r * 64 + ((lq ^ (r & 7)) * 8);
  }
  f32x4 acc[4][4];
#pragma unroll
  for (int m = 0; m < 4; ++m)
#pragma unroll
    for (int n = 0; n < 4; ++n) acc[m][n] = (f32x4){0.f, 0.f, 0.f, 0.f};

#define STGA1(t, cb)                                                        \
  { _Pragma("unroll") for (int j = 0; j < 2; ++j)                            \
      gl16(aptr + (size_t)aofs[j] + (size_t)(t) * 128,                       \
           &lds[(cb) + (j * 512 + wid * 64) * 8]); }
#define STGB1(h, t, cb)                                                     \
  { _Pragma("unroll") for (int j = 0; j < 2; ++j)                            \
      gl16(bptr + (size_t)bofs[h][j] + (size_t)(t) * 128,                    \
           &lds[(cb) + 8192 + (h) * 8192 + (j * 512 + wid * 64) * 8]); }

  const int NT = DIN / 64;                     // 16
  STGA1(0, 0); STGB1(0, 0, 0); STGB1(1, 0, 0);
  STGA1(1, 24576); STGB1(0, 1, 24576);
  asm volatile("s_waitcnt vmcnt(4)" ::: "memory");
  BAR;

  for (int t = 0; t < NT; ++t) {
    const int cb = (t & 1) * 24576;
    const int ncb = cb ^ 24576;
    const u16* bufc = &lds[cb];
    short8v A0[4], A1[4], Bk0[4], Bk1[4];
    // ---- phase 1: k0 ----
#pragma unroll
    for (int m = 0; m < 4; ++m) A0[m] = *(const short8v*)&bufc[aoff[m]];
#pragma unroll
    for (int n = 0; n < 4; ++n) Bk0[n] = *(const short8v*)&bufc[boff[n]];
    if (t + 1 < NT) STGB1(1, t + 1, ncb);
    BAR;
    __builtin_amdgcn_s_setprio(1);
#pragma unroll
    for (int m = 0; m < 4; ++m)
#pragma unroll
      for (int n = 0; n < 4; ++n)
        acc[m][n] = MFMA(A0[m], Bk0[n], acc[m][n], 0, 0, 0);
    __builtin_amdgcn_s_setprio(0);
    BAR;
    // ---- phase 2: k1 ----
#pragma unroll
    for (int m = 0; m < 4; ++m) A1[m] = *(const short8v*)&bufc[aoff[m] ^ 32];
#pragma unroll
    for (int n = 0; n < 4; ++n) Bk1[n] = *(const short8v*)&bufc[boff[n] ^ 32];
    if (t + 2 < NT) { STGA1(t + 2, cb); STGB1(0, t + 2, cb); }
    BAR;
    __builtin_amdgcn_s_setprio(1);
#pragma unroll
    for (int m = 0; m < 4; ++m)
#pragma unroll
      for (int n = 0; n < 4; ++n)
        acc[m][n] = MFMA(A1[m], Bk1[n], acc[m][n], 0, 0, 0);
    __builtin_amdgcn_s_setprio(0);
    if (t < NT - 2) asm volatile("s_waitcnt vmcnt(4)" ::: "memory");
    else            asm volatile("s_waitcnt vmcnt(0)" ::: "memory");
    BAR;
  }
  const float* b1e = b1 + e * DHID;
#pragma unroll
  for (int m = 0; m < 4; ++m)
#pragma unroll
    for (int j = 0; j < 4; ++j) {
      int rl = (wid >> 2) * 64 + m * 16 + lq * 4 + j;
      if (mt * 128 + rl < cn) {
        size_t orow = (size_t)(base + mt * 128 + rl) * DHID;
#pragma unroll
        for (int n = 0; n < 4; ++n) {
          int col = n0 + (wid & 3) * 64 + n * 16 + l15;
          float v = acc[m][n][j] + b1e[col];
          H[orow + col] = f2b(fmaxf(v, 0.f));
        }
      }
    }
}

// -------- GEMM 2: out[token] += w * (H @ W2 + b2)  (f32 atomic, 2 adds/cell) --------
__global__ __launch_bounds__(512, 1) void mlp2_k(
    const u16* __restrict__ H, const u16* __restrict__ W2T,
    const float* __restrict__ b2, const int* __restrict__ slots,
    const int* __restrict__ prefix, const int* __restrict__ cnt,
    const u32* __restrict__ ttab, const int* __restrict__ ntt,
    const float* __restrict__ topw, float* __restrict__ out) {
  const int ntt_ = *ntt;
  const int tot = 4 * ntt_;                    // nbx = DOUT/256 = 4
  int L = blockIdx.x;
  if (L >= tot) return;
  int w = xcd_swz(L, tot);
  const int bx = w / ntt_, ti = w - bx * ntt_;
  const u32 ent = ttab[ti];
  const int e = (int)(ent >> 16), mt = (int)(ent & 0xffffu);
  const int cn = cnt[e], base = prefix[e];
  const int n0 = bx * 256;
  __shared__ __align__(16) u16 lds[49152];
  const int tid = threadIdx.x, lane = tid & 63, wid = tid >> 6;
  const int l15 = lane & 15, lq = lane >> 4;
  const int tr = tid >> 3;
  const u32 swzo = (u32)(((tid & 7) ^ (tr & 7)) * 16);
  u32 aofs[2], bofs[2][2];
#pragma unroll
  for (int j = 0; j < 2; ++j) {
    int r = j * 64 + tr;
    int spos = imin(base + mt * 128 + r, NSLOT - 1);
    aofs[j] = (u32)spos * 4096u + swzo;
#pragma unroll
    for (int h = 0; h < 2; ++h)
      bofs[h][j] = (u32)(e * 1024 + n0 + h * 128 + j * 64 + tr) * 4096u + swzo;
  }
  const char* aptr = (const char*)H;
  const char* bptr = (const char*)W2T;
  int aoff[4], boff[4];
#pragma unroll
  for (int m = 0; m < 4; ++m) {
    int r = (wid >> 2) * 64 + m * 16 + l15;
    aoff[m] = r * 64 + ((lq ^ (r & 7)) * 8);
  }
#pragma unroll
  for (int n = 0; n < 4; ++n) {
    int r = (wid & 3) * 64 + n * 16 + l15;
    boff[n] = 8192 + r * 64 + ((lq ^ (r & 7)) * 8);
  }
  f32x4 acc[4][4];
#pragma unroll
  for (int m = 0; m < 4; ++m)
#pragma unroll
    for (int n = 0; n < 4; ++n) acc[m][n] = (f32x4){0.f, 0.f, 0.f, 0.f};

#define STGA2(t, cb)                                                        \
  { _Pragma("unroll") for (int j = 0; j < 2; ++j)                            \
      gl16(aptr + (size_t)aofs[j] + (size_t)(t) * 128,                       \
           &lds[(cb) + (j * 512 + wid * 64) * 8]); }
#define STGB2(h, t, cb)                                                     \
  { _Pragma("unroll") for (int j = 0; j < 2; ++j)                            \
      gl16(bptr + (size_t)bofs[h][j] + (size_t)(t) * 128,                    \
           &lds[(cb) + 8192 + (h) * 8192 + (j * 512 + wid * 64) * 8]); }

  const int NT = DHID / 64;                    // 32
  STGA2(0, 0); STGB2(0, 0, 0); STGB2(1, 0, 0);
  STGA2(1, 24576); STGB2(0, 1, 24576);
  asm volatile("s_waitcnt vmcnt(4)" ::: "memory");
  BAR;

  for (int t = 0; t < NT; ++t) {
    const int cb = (t & 1) * 24576;
    const int ncb = cb ^ 24576;
    const u16* bufc = &lds[cb];
    short8v A0[4], A1[4], Bk0[4], Bk1[4];
#pragma unroll
    for (int m = 0; m < 4; ++m) A0[m] = *(const short8v*)&bufc[aoff[m]];
#pragma unroll
    for (int n = 0; n < 4; ++n) Bk0[n] = *(const short8v*)&bufc[boff[n]];
    if (t + 1 < NT) STGB2(1, t + 1, ncb);
    BAR;
    __builtin_amdgcn_s_setprio(1);
#pragma unroll
    for (int m = 0; m < 4; ++m)
#pragma unroll
      for (int n = 0; n < 4; ++n)
        acc[m][n] = MFMA(A0[m], Bk0[n], acc[m][n], 0, 0, 0);
    __builtin_amdgcn_s_setprio(0);
    BAR;
#pragma unroll
    for (int m = 0; m < 4; ++m) A1[m] = *(const short8v*)&bufc[aoff[m] ^ 32];
#pragma unroll
    for (int n = 0; n < 4; ++n) Bk1[n] = *(const short8v*)&bufc[boff[n] ^ 32];
    if (t + 2 < NT) { STGA2(t + 2, cb); STGB2(0, t + 2, cb); }
    BAR;
    __builtin_amdgcn_s_setprio(1);
#pragma unroll
    for (int m = 0; m < 4; ++m)
#pragma unroll
      for (int n = 0; n < 4; ++n)
        acc[m][n] = MFMA(A1[m], Bk1[n], acc[m][n], 0, 0, 0);
    __builtin_amdgcn_s_setprio(0);
    if (t < NT - 2) asm volatile("s_waitcnt vmcnt(4)" ::: "memory");
    else            asm volatile("s_waitcnt vmcnt(0)" ::: "memory");
    BAR;
  }
  const float* b2e = b2 + e * DOUT;
#pragma unroll
  for (int m = 0; m < 4; ++m)
#pragma unroll
    for (int j = 0; j < 4; ++j) {
      int rl = (wid >> 2) * 64 + m * 16 + lq * 4 + j;
      if (mt * 128 + rl < cn) {
        int sc = slots[base + mt * 128 + rl];
        float wgt = topw[sc];
        size_t orow = (size_t)(sc >> 1) * DOUT;   // token row
#pragma unroll
        for (int n = 0; n < 4; ++n) {
          int col = n0 + (wid & 3) * 64 + n * 16 + l15;
          atomicAdd(&out[orow + col], wgt * (acc[m][n][j] + b2e[col]));
        }
      }
    }
}

extern "C" void kernel_launch(void* const* d_in, const int* in_sizes, int n_in,
                              void* d_out, int out_size, void* d_ws, size_t ws_size,
                              hipStream_t stream) {
  const float* x  = (const float*)d_in[0];
  const float* Wg = (const float*)d_in[1];
  const float* W1 = (const float*)d_in[2];
  const float* b1 = (const float*)d_in[3];
  const float* W2 = (const float*)d_in[4];
  const float* b2 = (const float*)d_in[5];
  float* out = (float*)d_out;
  char* ws = (char*)d_ws;

  int*    cnt    = (int*)(ws + OFF_CNT);
  int*    cursor = (int*)(ws + OFF_CURSOR);
  int*    prefix = (int*)(ws + OFF_PREFIX);
  u32*    ttab   = (u32*)(ws + OFF_TTAB);
  int*    ntt    = (int*)(ws + OFF_NTT);
  int2*   topidx = (int2*)(ws + OFF_TOPIDX);
  float2* topw2  = (float2*)(ws + OFF_TOPW);
  float*  topw   = (float*)(ws + OFF_TOPW);
  int*    slots  = (int*)(ws + OFF_SLOTS);
  u16*    xb     = (u16*)(ws + OFF_XB);
  u16*    W1T    = (u16*)(ws + OFF_W1T);
  u16*    W2T    = (u16*)(ws + OFF_W2T);
  u16*    H      = (u16*)(ws + OFF_H);

  (void)hipMemsetAsync(ws, 0, 256, stream);                          // cnt/cursor/prefix
  (void)hipMemsetAsync(out, 0, (size_t)out_size * sizeof(float), stream);  // atomic base

  transpose_conv_k<<<dim3(DHID / 64, DIN / 64, NE), 256, 0, stream>>>(W1, W1T, DIN, DHID);
  transpose_conv_k<<<dim3(DHID / 64 / 2, DIN / 64 * 2, NE), 256, 0, stream>>>(W2, W2T, DHID, DOUT);
  gating2_k<<<256, 256, 0, stream>>>(x, Wg, topidx, topw2, cnt, xb);
  prefix_k<<<1, 64, 0, stream>>>(cnt, prefix, cursor, ttab, ntt);
  scatter_k<<<BQ / 256, 256, 0, stream>>>(topidx, cursor, slots);
  mlp1_k<<<8 * MAXT, 512, 0, stream>>>(xb, W1T, b1, slots, prefix, cnt, ttab, ntt, H);
  mlp2_k<<<4 * MAXT, 512, 0, stream>>>(H, W2T, b2, slots, prefix, cnt, ttab, ntt, topw, out);
}

// Round 15
// 400.088 us; speedup vs baseline: 1.2114x; 1.2114x over previous
//
#include <hip/hip_runtime.h>

typedef unsigned short u16;
typedef unsigned int   u32;

typedef __attribute__((ext_vector_type(8))) short short8v;
typedef __attribute__((ext_vector_type(4))) float f32x4;

// ---------------- problem constants ----------------
#define BQ   8192
#define DIN  1024
#define DHID 2048
#define DOUT 1024
#define NE   16
#define NSLOT (BQ*2)
#define MAXT 144         // sum ceil(cnt_e/128) <= 128 + 16

// ---------------- ws layout (bytes) ----------------
#define OFF_CNT    ((size_t)0)
#define OFF_CURSOR ((size_t)64)
#define OFF_PREFIX ((size_t)128)
#define OFF_TTAB   ((size_t)512)
#define OFF_NTT    ((size_t)2048)
#define OFF_TOPIDX ((size_t)4096)
#define OFF_TOPW   (OFF_TOPIDX + (size_t)65536)
#define OFF_SLOTS  (OFF_TOPW   + (size_t)65536)
#define OFF_POSOF  (OFF_SLOTS  + (size_t)65536)
#define MB (size_t)(1u<<20)
#define OFF_XB     (1*MB)
#define OFF_W1T    (OFF_XB  + 16*MB)
#define OFF_W2T    (OFF_W1T + 64*MB)
#define OFF_H      (OFF_W2T + 64*MB)
#define OFF_POUT   (OFF_H   + 64*MB)   // bf16 partials, 32MB

__device__ __forceinline__ u16 f2b(float f) {        // f32 -> bf16 RNE
  u32 u = __float_as_uint(f);
  u += 0x7fffu + ((u >> 16) & 1u);
  return (u16)(u >> 16);
}

__device__ __forceinline__ float b2f(u16 u) {
  return __uint_as_float(((u32)u) << 16);
}

__device__ __forceinline__ void gl16(const void* g, void* l) {
  __builtin_amdgcn_global_load_lds(
      (const __attribute__((address_space(1))) u32*)g,
      (__attribute__((address_space(3))) u32*)l, 16, 0, 0);
}

__device__ __forceinline__ int imin(int a, int b) { return a < b ? a : b; }

// bijective XCD-chunked block swizzle (m204)
__device__ __forceinline__ int xcd_swz(int L, int total) {
  int q = total >> 3, r = total & 7;
  int c = L & 7, p = L >> 3;
  return (c < r ? c * (q + 1) : r * (q + 1) + (c - r) * q) + p;
}

#define FENCE asm volatile("" ::: "memory")
#define BAR   do { FENCE; __builtin_amdgcn_s_barrier(); FENCE; } while (0)
#define MFMA  __builtin_amdgcn_mfma_f32_16x16x32_bf16

// ------- prepass: per-expert transpose+convert: in[R][C] f32 -> out[C][R] bf16 -------
__global__ void transpose_conv_k(const float* __restrict__ in, u16* __restrict__ out,
                                 int R, int C) {
  __shared__ __align__(16) u16 tile[64][68];
  const int e = blockIdx.z;
  const float* ip = in + (size_t)e * R * C;
  u16* op = out + (size_t)e * R * C;
  const int r0 = blockIdx.y * 64, c0 = blockIdx.x * 64;
  const int tr = threadIdx.x >> 4, tc = threadIdx.x & 15;
#pragma unroll
  for (int i = 0; i < 4; ++i) {
    int r = tr + i * 16;
    float4 v = *(const float4*)(ip + (size_t)(r0 + r) * C + c0 + tc * 4);
    ushort4 b; b.x=f2b(v.x); b.y=f2b(v.y); b.z=f2b(v.z); b.w=f2b(v.w);
    *(ushort4*)&tile[r][tc * 4] = b;
  }
  __syncthreads();
#pragma unroll
  for (int i = 0; i < 4; ++i) {
    int c = i * 16 + (threadIdx.x >> 4);
    int rq = threadIdx.x & 15;
    ushort4 b;
    b.x = tile[rq*4+0][c]; b.y = tile[rq*4+1][c];
    b.z = tile[rq*4+2][c]; b.w = tile[rq*4+3][c];
    *(ushort4*)(op + (size_t)(c0 + c) * R + r0 + rq * 4) = b;
  }
}

// ---------- gating (+ fused x->bf16 convert): Wg in LDS, 8 thr/token, fp64 ----------
__global__ __launch_bounds__(256) void gating2_k(
    const float* __restrict__ x, const float* __restrict__ Wg,
    int2* __restrict__ topidx, float2* __restrict__ topw, int* __restrict__ cnt,
    u16* __restrict__ xb) {
  __shared__ __align__(16) float wg[1024 * 16];
  __shared__ int hist[16];
  const int tid = threadIdx.x;
  const int t0 = blockIdx.x * 32;
  if (tid < 16) hist[tid] = 0;
  for (int idx = tid; idx < 4096; idx += 256) {
    int k = idx >> 2, c = idx & 3;
    float4 v = ((const float4*)Wg)[idx];
    int pc = c ^ ((k >> 7) & 3);
    *(float4*)&wg[k * 16 + pc * 4] = v;
  }
  __syncthreads();
  const int tt = tid >> 3, q = tid & 7;
  const int f = q & 3;
  double p[16];
#pragma unroll
  for (int e = 0; e < 16; ++e) p[e] = 0.0;
  const float4* xr4 = (const float4*)(x + (size_t)(t0 + tt) * DIN + q * 128);
  for (int jj = 0; jj < 32; ++jj) {
    float4 xv = xr4[jj];
#pragma unroll
    for (int u = 0; u < 4; ++u) {
      int row = q * 128 + jj * 4 + u;
      float xs = (u == 0) ? xv.x : (u == 1) ? xv.y : (u == 2) ? xv.z : xv.w;
      double xd = (double)xs;
#pragma unroll
      for (int c = 0; c < 4; ++c) {
        float4 w = *(const float4*)&wg[row * 16 + (c ^ f) * 4];
        p[c * 4 + 0] += xd * (double)w.x;
        p[c * 4 + 1] += xd * (double)w.y;
        p[c * 4 + 2] += xd * (double)w.z;
        p[c * 4 + 3] += xd * (double)w.w;
      }
    }
  }
#pragma unroll
  for (int e = 0; e < 16; ++e) {
    double v = p[e];
    v += __shfl_xor(v, 1);
    v += __shfl_xor(v, 2);
    v += __shfl_xor(v, 4);
    p[e] = v;
  }
  if (q == 0) {
    double m0 = -1e300, m1 = -1e300; int i0 = 0, i1 = 0;
#pragma unroll
    for (int e = 0; e < 16; ++e) {
      double v = p[e];
      if (v > m0) { m1 = m0; i1 = i0; m0 = v; i0 = e; }
      else if (v > m1) { m1 = v; i1 = e; }
    }
    double r = exp(m1 - m0);
    double w0 = 1.0 / (1.0 + r);
    int t = t0 + tt;
    topidx[t] = make_int2(i0, i1);
    topw[t] = make_float2((float)w0, (float)(r / (1.0 + r)));
    atomicAdd(&hist[i0], 1);
    atomicAdd(&hist[i1], 1);
  }
  // fused convert of this block's 32 token rows (x hot in L1/L2)
  const float4* ip = (const float4*)x;
#pragma unroll
  for (int i = 0; i < 16; ++i) {
    int idx = i * 256 + tid;
    size_t g = (size_t)t0 * 128 + idx;
    float4 a = ip[g * 2], b = ip[g * 2 + 1];
    union { u16 u[8]; uint4 v; } r;
    r.u[0]=f2b(a.x); r.u[1]=f2b(a.y); r.u[2]=f2b(a.z); r.u[3]=f2b(a.w);
    r.u[4]=f2b(b.x); r.u[5]=f2b(b.y); r.u[6]=f2b(b.z); r.u[7]=f2b(b.w);
    ((uint4*)xb)[g] = r.v;
  }
  __syncthreads();
  if (tid < 16 && hist[tid] > 0) atomicAdd(&cnt[tid], hist[tid]);
}

// prefix + compact tile table: entries (e<<16)|mt, mt over ceil(cnt/128)
__global__ void prefix_k(const int* __restrict__ cnt, int* __restrict__ prefix,
                         int* __restrict__ cursor, u32* __restrict__ ttab,
                         int* __restrict__ ntt) {
  if (threadIdx.x == 0) {
    int s = 0, nt = 0;
    for (int e = 0; e < 16; ++e) {
      prefix[e] = s; cursor[e] = s; s += cnt[e];
      int mts = (cnt[e] + 127) >> 7;
      for (int m = 0; m < mts; ++m) ttab[nt++] = ((u32)e << 16) | (u32)m;
    }
    prefix[16] = s;
    *ntt = nt;
  }
}

__global__ void scatter_k(const int2* __restrict__ topidx, int* __restrict__ cursor,
                          int* __restrict__ slots, int* __restrict__ posof) {
  int t = blockIdx.x * 256 + threadIdx.x;
  int2 e = topidx[t];
  int p0 = atomicAdd(&cursor[e.x], 1); slots[p0] = t * 2 + 0; posof[t * 2 + 0] = p0;
  int p1 = atomicAdd(&cursor[e.y], 1); slots[p1] = t * 2 + 1; posof[t * 2 + 1] = p1;
}

// =====================================================================
// grouped GEMM: BM=128, BN=256, BK=64, 512 thr (8 waves, 2Mx4N, 64x64/wave).
// 2 phases/K-tile, 16 MFMA/phase. LDS: 2 buf x {A 16KB | Blo 16KB | Bhi 16KB}
// = 96KB. Stage units: ph1 -> Bhi(t+1); ph2 -> A(t+2), Blo(t+2).
// Boundary s_waitcnt vmcnt(4): 4 newest = {A(t+2),Blo(t+2)} => t+1 landed.
// Chunk swizzle: phys 16B chunk = global chunk ^ (row&7), both sides.
// (round-11 structure, verified passing; all addresses consumed by the
// prologue so no global load can sink into the counted-vmcnt loop.)
// =====================================================================

// -------- GEMM 1: H = relu(gather(xb) @ W1 + b1) --------
__global__ __launch_bounds__(512, 1) void mlp1_k(
    const u16* __restrict__ xb, const u16* __restrict__ W1T,
    const float* __restrict__ b1, const int* __restrict__ slots,
    const int* __restrict__ prefix, const int* __restrict__ cnt,
    const u32* __restrict__ ttab, const int* __restrict__ ntt,
    u16* __restrict__ H) {
  const int ntt_ = *ntt;
  const int tot = 8 * ntt_;                    // nbx = DHID/256 = 8
  int L = blockIdx.x;
  if (L >= tot) return;
  int w = xcd_swz(L, tot);
  const int bx = w / ntt_, ti = w - bx * ntt_;
  const u32 ent = ttab[ti];
  const int e = (int)(ent >> 16), mt = (int)(ent & 0xffffu);
  const int cn = cnt[e], base = prefix[e];
  const int n0 = bx * 256;
  __shared__ __align__(16) u16 lds[49152];     // 96KB
  const int tid = threadIdx.x, lane = tid & 63, wid = tid >> 6;
  const int l15 = lane & 15, lq = lane >> 4;
  const int tr = tid >> 3;
  const u32 swzo = (u32)(((tid & 7) ^ (tr & 7)) * 16);
  // staging sources: A rows j*64+tr (128 rows), B rows h*128+j*64+tr (256 rows)
  u32 aofs[2], bofs[2][2];
#pragma unroll
  for (int j = 0; j < 2; ++j) {
    int r = j * 64 + tr;
    int sidx = imin(base + mt * 128 + r, NSLOT - 1);
    int tok = slots[sidx] >> 1;
    aofs[j] = (u32)tok * 2048u + swzo;
#pragma unroll
    for (int h = 0; h < 2; ++h)
      bofs[h][j] = (u32)(e * 2048 + n0 + h * 128 + j * 64 + tr) * 2048u + swzo;
  }
  const char* aptr = (const char*)xb;
  const char* bptr = (const char*)W1T;
  int aoff[4], boff[4];
#pragma unroll
  for (int m = 0; m < 4; ++m) {
    int r = (wid >> 2) * 64 + m * 16 + l15;
    aoff[m] = r * 64 + ((lq ^ (r & 7)) * 8);
  }
#pragma unroll
  for (int n = 0; n < 4; ++n) {
    int r = (wid & 3) * 64 + n * 16 + l15;
    boff[n] = 8192 + r * 64 + ((lq ^ (r & 7)) * 8);
  }
  f32x4 acc[4][4];
#pragma unroll
  for (int m = 0; m < 4; ++m)
#pragma unroll
    for (int n = 0; n < 4; ++n) acc[m][n] = (f32x4){0.f, 0.f, 0.f, 0.f};

#define STGA1(t, cb)                                                        \
  { _Pragma("unroll") for (int j = 0; j < 2; ++j)                            \
      gl16(aptr + (size_t)aofs[j] + (size_t)(t) * 128,                       \
           &lds[(cb) + (j * 512 + wid * 64) * 8]); }
#define STGB1(h, t, cb)                                                     \
  { _Pragma("unroll") for (int j = 0; j < 2; ++j)                            \
      gl16(bptr + (size_t)bofs[h][j] + (size_t)(t) * 128,                    \
           &lds[(cb) + 8192 + (h) * 8192 + (j * 512 + wid * 64) * 8]); }

  const int NT = DIN / 64;                     // 16
  STGA1(0, 0); STGB1(0, 0, 0); STGB1(1, 0, 0);
  STGA1(1, 24576); STGB1(0, 1, 24576);
  asm volatile("s_waitcnt vmcnt(4)" ::: "memory");
  BAR;

  for (int t = 0; t < NT; ++t) {
    const int cb = (t & 1) * 24576;
    const int ncb = cb ^ 24576;
    const u16* bufc = &lds[cb];
    short8v A0[4], A1[4], Bk0[4], Bk1[4];
    // ---- phase 1: k0 ----
#pragma unroll
    for (int m = 0; m < 4; ++m) A0[m] = *(const short8v*)&bufc[aoff[m]];
#pragma unroll
    for (int n = 0; n < 4; ++n) Bk0[n] = *(const short8v*)&bufc[boff[n]];
    if (t + 1 < NT) STGB1(1, t + 1, ncb);
    BAR;
    __builtin_amdgcn_s_setprio(1);
#pragma unroll
    for (int m = 0; m < 4; ++m)
#pragma unroll
      for (int n = 0; n < 4; ++n)
        acc[m][n] = MFMA(A0[m], Bk0[n], acc[m][n], 0, 0, 0);
    __builtin_amdgcn_s_setprio(0);
    BAR;
    // ---- phase 2: k1 ----
#pragma unroll
    for (int m = 0; m < 4; ++m) A1[m] = *(const short8v*)&bufc[aoff[m] ^ 32];
#pragma unroll
    for (int n = 0; n < 4; ++n) Bk1[n] = *(const short8v*)&bufc[boff[n] ^ 32];
    if (t + 2 < NT) { STGA1(t + 2, cb); STGB1(0, t + 2, cb); }
    BAR;
    __builtin_amdgcn_s_setprio(1);
#pragma unroll
    for (int m = 0; m < 4; ++m)
#pragma unroll
      for (int n = 0; n < 4; ++n)
        acc[m][n] = MFMA(A1[m], Bk1[n], acc[m][n], 0, 0, 0);
    __builtin_amdgcn_s_setprio(0);
    if (t < NT - 2) asm volatile("s_waitcnt vmcnt(4)" ::: "memory");
    else            asm volatile("s_waitcnt vmcnt(0)" ::: "memory");
    BAR;
  }
  const float* b1e = b1 + e * DHID;
#pragma unroll
  for (int m = 0; m < 4; ++m)
#pragma unroll
    for (int j = 0; j < 4; ++j) {
      int rl = (wid >> 2) * 64 + m * 16 + lq * 4 + j;
      if (mt * 128 + rl < cn) {
        size_t orow = (size_t)(base + mt * 128 + rl) * DHID;
#pragma unroll
        for (int n = 0; n < 4; ++n) {
          int col = n0 + (wid & 3) * 64 + n * 16 + l15;
          float v = acc[m][n][j] + b1e[col];
          H[orow + col] = f2b(fmaxf(v, 0.f));
        }
      }
    }
}

// -------- GEMM 2: pout_bf16 = w * (H @ W2 + b2) --------
__global__ __launch_bounds__(512, 1) void mlp2_k(
    const u16* __restrict__ H, const u16* __restrict__ W2T,
    const float* __restrict__ b2, const int* __restrict__ slots,
    const int* __restrict__ prefix, const int* __restrict__ cnt,
    const u32* __restrict__ ttab, const int* __restrict__ ntt,
    const float* __restrict__ topw, u16* __restrict__ pout) {
  const int ntt_ = *ntt;
  const int tot = 4 * ntt_;                    // nbx = DOUT/256 = 4
  int L = blockIdx.x;
  if (L >= tot) return;
  int w = xcd_swz(L, tot);
  const int bx = w / ntt_, ti = w - bx * ntt_;
  const u32 ent = ttab[ti];
  const int e = (int)(ent >> 16), mt = (int)(ent & 0xffffu);
  const int cn = cnt[e], base = prefix[e];
  const int n0 = bx * 256;
  __shared__ __align__(16) u16 lds[49152];
  const int tid = threadIdx.x, lane = tid & 63, wid = tid >> 6;
  const int l15 = lane & 15, lq = lane >> 4;
  const int tr = tid >> 3;
  const u32 swzo = (u32)(((tid & 7) ^ (tr & 7)) * 16);
  u32 aofs[2], bofs[2][2];
#pragma unroll
  for (int j = 0; j < 2; ++j) {
    int r = j * 64 + tr;
    int spos = imin(base + mt * 128 + r, NSLOT - 1);
    aofs[j] = (u32)spos * 4096u + swzo;
#pragma unroll
    for (int h = 0; h < 2; ++h)
      bofs[h][j] = (u32)(e * 1024 + n0 + h * 128 + j * 64 + tr) * 4096u + swzo;
  }
  const char* aptr = (const char*)H;
  const char* bptr = (const char*)W2T;
  int aoff[4], boff[4];
#pragma unroll
  for (int m = 0; m < 4; ++m) {
    int r = (wid >> 2) * 64 + m * 16 + l15;
    aoff[m] = r * 64 + ((lq ^ (r & 7)) * 8);
  }
#pragma unroll
  for (int n = 0; n < 4; ++n) {
    int r = (wid & 3) * 64 + n * 16 + l15;
    boff[n] = 8192 + r * 64 + ((lq ^ (r & 7)) * 8);
  }
  f32x4 acc[4][4];
#pragma unroll
  for (int m = 0; m < 4; ++m)
#pragma unroll
    for (int n = 0; n < 4; ++n) acc[m][n] = (f32x4){0.f, 0.f, 0.f, 0.f};

#define STGA2(t, cb)                                                        \
  { _Pragma("unroll") for (int j = 0; j < 2; ++j)                            \
      gl16(aptr + (size_t)aofs[j] + (size_t)(t) * 128,                       \
           &lds[(cb) + (j * 512 + wid * 64) * 8]); }
#define STGB2(h, t, cb)                                                     \
  { _Pragma("unroll") for (int j = 0; j < 2; ++j)                            \
      gl16(bptr + (size_t)bofs[h][j] + (size_t)(t) * 128,                    \
           &lds[(cb) + 8192 + (h) * 8192 + (j * 512 + wid * 64) * 8]); }

  const int NT = DHID / 64;                    // 32
  STGA2(0, 0); STGB2(0, 0, 0); STGB2(1, 0, 0);
  STGA2(1, 24576); STGB2(0, 1, 24576);
  asm volatile("s_waitcnt vmcnt(4)" ::: "memory");
  BAR;

  for (int t = 0; t < NT; ++t) {
    const int cb = (t & 1) * 24576;
    const int ncb = cb ^ 24576;
    const u16* bufc = &lds[cb];
    short8v A0[4], A1[4], Bk0[4], Bk1[4];
#pragma unroll
    for (int m = 0; m < 4; ++m) A0[m] = *(const short8v*)&bufc[aoff[m]];
#pragma unroll
    for (int n = 0; n < 4; ++n) Bk0[n] = *(const short8v*)&bufc[boff[n]];
    if (t + 1 < NT) STGB2(1, t + 1, ncb);
    BAR;
    __builtin_amdgcn_s_setprio(1);
#pragma unroll
    for (int m = 0; m < 4; ++m)
#pragma unroll
      for (int n = 0; n < 4; ++n)
        acc[m][n] = MFMA(A0[m], Bk0[n], acc[m][n], 0, 0, 0);
    __builtin_amdgcn_s_setprio(0);
    BAR;
#pragma unroll
    for (int m = 0; m < 4; ++m) A1[m] = *(const short8v*)&bufc[aoff[m] ^ 32];
#pragma unroll
    for (int n = 0; n < 4; ++n) Bk1[n] = *(const short8v*)&bufc[boff[n] ^ 32];
    if (t + 2 < NT) { STGA2(t + 2, cb); STGB2(0, t + 2, cb); }
    BAR;
    __builtin_amdgcn_s_setprio(1);
#pragma unroll
    for (int m = 0; m < 4; ++m)
#pragma unroll
      for (int n = 0; n < 4; ++n)
        acc[m][n] = MFMA(A1[m], Bk1[n], acc[m][n], 0, 0, 0);
    __builtin_amdgcn_s_setprio(0);
    if (t < NT - 2) asm volatile("s_waitcnt vmcnt(4)" ::: "memory");
    else            asm volatile("s_waitcnt vmcnt(0)" ::: "memory");
    BAR;
  }
  const float* b2e = b2 + e * DOUT;
#pragma unroll
  for (int m = 0; m < 4; ++m)
#pragma unroll
    for (int j = 0; j < 4; ++j) {
      int rl = (wid >> 2) * 64 + m * 16 + lq * 4 + j;
      if (mt * 128 + rl < cn) {
        int spos = base + mt * 128 + rl;
        float wgt = topw[slots[spos]];
        size_t orow = (size_t)spos * DOUT;
#pragma unroll
        for (int n = 0; n < 4; ++n) {
          int col = n0 + (wid & 3) * 64 + n * 16 + l15;
          pout[orow + col] = f2b(wgt * (acc[m][n][j] + b2e[col]));
        }
      }
    }
}

// ---------------- combine: out[t] = pout[pos(t,0)] + pout[pos(t,1)]  (bf16 partials) ----------------
__global__ void combine_k(const u16* __restrict__ pout, const int* __restrict__ posof,
                          float* __restrict__ out) {
  int t = blockIdx.x;
  int p0 = posof[t * 2], p1 = posof[t * 2 + 1];
  const ushort4* r0 = (const ushort4*)(pout + (size_t)p0 * DOUT);
  const ushort4* r1 = (const ushort4*)(pout + (size_t)p1 * DOUT);
  ushort4 a = r0[threadIdx.x], b = r1[threadIdx.x];
  float4 o;
  o.x = b2f(a.x) + b2f(b.x);
  o.y = b2f(a.y) + b2f(b.y);
  o.z = b2f(a.z) + b2f(b.z);
  o.w = b2f(a.w) + b2f(b.w);
  ((float4*)(out + (size_t)t * DOUT))[threadIdx.x] = o;
}

extern "C" void kernel_launch(void* const* d_in, const int* in_sizes, int n_in,
                              void* d_out, int out_size, void* d_ws, size_t ws_size,
                              hipStream_t stream) {
  const float* x  = (const float*)d_in[0];
  const float* Wg = (const float*)d_in[1];
  const float* W1 = (const float*)d_in[2];
  const float* b1 = (const float*)d_in[3];
  const float* W2 = (const float*)d_in[4];
  const float* b2 = (const float*)d_in[5];
  float* out = (float*)d_out;
  char* ws = (char*)d_ws;

  int*    cnt    = (int*)(ws + OFF_CNT);
  int*    cursor = (int*)(ws + OFF_CURSOR);
  int*    prefix = (int*)(ws + OFF_PREFIX);
  u32*    ttab   = (u32*)(ws + OFF_TTAB);
  int*    ntt    = (int*)(ws + OFF_NTT);
  int2*   topidx = (int2*)(ws + OFF_TOPIDX);
  float2* topw2  = (float2*)(ws + OFF_TOPW);
  float*  topw   = (float*)(ws + OFF_TOPW);
  int*    slots  = (int*)(ws + OFF_SLOTS);
  int*    posof  = (int*)(ws + OFF_POSOF);
  u16*    xb     = (u16*)(ws + OFF_XB);
  u16*    W1T    = (u16*)(ws + OFF_W1T);
  u16*    W2T    = (u16*)(ws + OFF_W2T);
  u16*    H      = (u16*)(ws + OFF_H);
  u16*    pout   = (u16*)(ws + OFF_POUT);

  (void)hipMemsetAsync(ws, 0, 256, stream);

  transpose_conv_k<<<dim3(DHID / 64, DIN / 64, NE), 256, 0, stream>>>(W1, W1T, DIN, DHID);
  transpose_conv_k<<<dim3(DHID / 64 / 2, DIN / 64 * 2, NE), 256, 0, stream>>>(W2, W2T, DHID, DOUT);
  gating2_k<<<256, 256, 0, stream>>>(x, Wg, topidx, topw2, cnt, xb);
  prefix_k<<<1, 64, 0, stream>>>(cnt, prefix, cursor, ttab, ntt);
  scatter_k<<<BQ / 256, 256, 0, stream>>>(topidx, cursor, slots, posof);
  mlp1_k<<<8 * MAXT, 512, 0, stream>>>(xb, W1T, b1, slots, prefix, cnt, ttab, ntt, H);
  mlp2_k<<<4 * MAXT, 512, 0, stream>>>(H, W2T, b2, slots, prefix, cnt, ttab, ntt, topw, pout);
  combine_k<<<BQ, 256, 0, stream>>>(pout, posof, out);
}